// Round 1
// baseline (82.187 us; speedup 1.0000x reference)
//
#include <hip/hip_runtime.h>

// Problem constants (reference: B,E,P,L,D = 16,2048,16384,5,64)
#define B 16
#define E 2048
#define P 16384
#define L 5
#define D 64
#define EPS 1e-9f

// Fused single-dispatch kernel, zero global workspace.
//
// Each block owns (batch b, path-chunk g). Phase A recomputes the per-batch
// projection table proj[e][l] = dot(emb[b,e,:], ev[l,:]) into LDS (40 KB);
// the 16x recompute across the batch's 16 blocks is cheap (655K FMA ~2.1us
// VALU, 512 KB L2-resident emb read ~3.7us/CU) and buys us: no 640 KB proj
// HBM round-trip, no d_ws use (dodges the 256 MB workspace re-poison fill
// that dominated the profile), and one dispatch instead of two.
//
// Block mapping co-locates all 16 blocks of a batch on one XCD (blockIdx&7
// ~ XCD on the 8-XCD round-robin) so emb[b] (512 KB) is pulled into that
// XCD's L2 once and served 16x from L2 instead of L3.
__global__ __launch_bounds__(512) void edge_fused_kernel(
    const float* __restrict__ emb, const int* __restrict__ paths,
    const float* __restrict__ ev, float* __restrict__ out) {
    __shared__ float sev[L * D];    // 1.25 KB
    __shared__ float sproj[E * L];  // 40 KB

    const int t    = threadIdx.x;
    const int xcd  = blockIdx.x & 7;
    const int slot = blockIdx.x >> 3;       // 0..31
    const int b    = xcd * 2 + (slot & 1);  // 0..15  (2 batches per XCD)
    const int g    = slot >> 1;             // 0..15  path chunk within batch

    // Prefetch this thread's path indices now — they are independent of
    // phase A, so their HBM latency hides under the projection compute.
    int pidx[2][L];
    const int pbase = g * (P / 16);  // 1024 paths per block
#pragma unroll
    for (int k = 0; k < 2; ++k) {
        const int* pp = paths + ((size_t)b * P + pbase + k * 512 + t) * L;
#pragma unroll
        for (int l = 0; l < L; ++l) pidx[k][l] = pp[l];
    }

    for (int i = t; i < L * D; i += 512) sev[i] = ev[i];
    __syncthreads();

    // Phase A: projection table. Half-row per thread (2 lanes per row,
    // shuffle-combine) -> 8 independent float4 loads in flight per pass.
    const int half = t & 1;
    const int rt   = t >> 1;  // 0..255 row-thread
    const float4* w4 = (const float4*)sev;
#pragma unroll
    for (int j = 0; j < E / 256; ++j) {  // 8 passes over the 2048 rows
        const int e = rt + j * 256;
        const float4* src =
            (const float4*)(emb + ((size_t)b * E + e) * D + half * 32);
        float acc[L] = {0.f, 0.f, 0.f, 0.f, 0.f};
#pragma unroll
        for (int c = 0; c < 8; ++c) {
            float4 v = src[c];
#pragma unroll
            for (int l = 0; l < L; ++l) {
                float4 w = w4[l * 16 + half * 8 + c];  // LDS broadcast
                acc[l] += v.x * w.x + v.y * w.y + v.z * w.z + v.w * w.w;
            }
        }
#pragma unroll
        for (int l = 0; l < L; ++l) acc[l] += __shfl_xor(acc[l], 1);
        if (half == 0) {
#pragma unroll
            for (int l = 0; l < L; ++l) sproj[e * L + l] = acc[l];
        }
    }
    __syncthreads();

    // Phase B: gather this block's 1024 paths from LDS.
#pragma unroll
    for (int k = 0; k < 2; ++k) {
        const int p = pbase + k * 512 + t;
        float sum = 0.f;
        int cnt = 0;
#pragma unroll
        for (int l = 0; l < L; ++l) {
            const int e = pidx[k][l];
            const bool valid = (e >= 0);
            const float v = sproj[(valid ? e : 0) * L + l];
            sum += valid ? v : 0.f;
            cnt += valid ? 1 : 0;
        }
        out[(size_t)b * P + p] = sum / ((float)cnt + EPS);
    }
}

extern "C" void kernel_launch(void* const* d_in, const int* in_sizes, int n_in,
                              void* d_out, int out_size, void* d_ws, size_t ws_size,
                              hipStream_t stream) {
    const float* emb   = (const float*)d_in[0];  // (B,E,D) f32
    const int*   paths = (const int*)d_in[1];    // (B,P,L) int32
    const float* ev    = (const float*)d_in[2];  // (L,D) f32
    float* out = (float*)d_out;                  // (B,P) f32
    (void)d_ws; (void)ws_size;                   // workspace intentionally unused

    edge_fused_kernel<<<256, 512, 0, stream>>>(emb, paths, ev, out);
}